// Round 3
// baseline (160.864 us; speedup 1.0000x reference)
//
#include <hip/hip_runtime.h>
#include <stdint.h>

#define B_ROWS 4096
#define D_DIM  512
#define N_TOT  8192
#define TEMP_INV 2.0f   // 1/0.5
#define NB     64       // N_TOT / 128 col/row tiles
#define NPAIR  1056     // sum over bi of ceil((NB-bi)/2)

typedef __bf16 bf16x8 __attribute__((ext_vector_type(8)));
typedef float  f32x4  __attribute__((ext_vector_type(4)));
typedef unsigned short ushort8 __attribute__((ext_vector_type(8)));

__device__ __forceinline__ unsigned short f2bf(float f) {
    union { float f; unsigned int u; } c; c.f = f;
    unsigned int u = c.u;
    return (unsigned short)((u + 0x7fffu + ((u >> 16) & 1u)) >> 16);
}

// async global->LDS, 16B per lane. LDS dest is wave-uniform base + lane*16.
__device__ __forceinline__ void gl_lds16(const void* g, void* l) {
    __builtin_amdgcn_global_load_lds(
        (__attribute__((address_space(1))) void*)(uintptr_t)g,
        (__attribute__((address_space(3))) void*)(uintptr_t)l,
        16, 0, 0);
}

// ------- kernel 1: fused L2-normalize (write bf16 z) + positive-pair dot -------
// also zero-inits rowsum[] and the completion counter for kernel 2's tail.
__global__ __launch_bounds__(256) void normpos_kernel(
    const float* __restrict__ xi, const float* __restrict__ xj,
    unsigned short* __restrict__ z, float* __restrict__ pos,
    float* __restrict__ rowsum, unsigned int* __restrict__ counter) {
    if (blockIdx.x < 32) rowsum[blockIdx.x * 256 + threadIdx.x] = 0.f;
    if (blockIdx.x == 32 && threadIdx.x == 0) *counter = 0u;

    const int wid  = threadIdx.x >> 6;
    const int lane = threadIdx.x & 63;
    const int k    = blockIdx.x * 4 + wid;
    const float4* a4 = (const float4*)(xi + (size_t)k * D_DIM);
    const float4* b4 = (const float4*)(xj + (size_t)k * D_DIM);
    float4 va0 = a4[2 * lane], va1 = a4[2 * lane + 1];
    float4 vb0 = b4[2 * lane], vb1 = b4[2 * lane + 1];
    float ssa = va0.x*va0.x + va0.y*va0.y + va0.z*va0.z + va0.w*va0.w
              + va1.x*va1.x + va1.y*va1.y + va1.z*va1.z + va1.w*va1.w;
    float ssb = vb0.x*vb0.x + vb0.y*vb0.y + vb0.z*vb0.z + vb0.w*vb0.w
              + vb1.x*vb1.x + vb1.y*vb1.y + vb1.z*vb1.z + vb1.w*vb1.w;
    float dot = va0.x*vb0.x + va0.y*vb0.y + va0.z*vb0.z + va0.w*vb0.w
              + va1.x*vb1.x + va1.y*vb1.y + va1.z*vb1.z + va1.w*vb1.w;
    #pragma unroll
    for (int m = 32; m >= 1; m >>= 1) {
        ssa += __shfl_xor(ssa, m);
        ssb += __shfl_xor(ssb, m);
        dot += __shfl_xor(dot, m);
    }
    const float rna = 1.0f / fmaxf(sqrtf(ssa), 1e-12f);
    const float rnb = 1.0f / fmaxf(sqrtf(ssb), 1e-12f);
    float av[8] = {va0.x, va0.y, va0.z, va0.w, va1.x, va1.y, va1.z, va1.w};
    float bv[8] = {vb0.x, vb0.y, vb0.z, vb0.w, vb1.x, vb1.y, vb1.z, vb1.w};
    union { ushort8 v; unsigned short s[8]; } oa, ob;
    #pragma unroll
    for (int i = 0; i < 8; ++i) {
        oa.s[i] = f2bf(av[i] * rna);
        ob.s[i] = f2bf(bv[i] * rnb);
    }
    *(ushort8*)(z + (size_t)k * D_DIM + lane * 8) = oa.v;
    *(ushort8*)(z + (size_t)(k + B_ROWS) * D_DIM + lane * 8) = ob.v;
    if (lane == 0) pos[k] = dot * rna * rnb;
}

// -------- kernel 2: symmetric Gram row-sums, 128x256 region per block --------
// Each block: A-tile rows [bi*128,+128), two B col-tiles {bi+2p, bi+2p+1}.
// 512 threads = 8 waves in a 2x4 grid, each wave 64x64 via 4x4 mfma 16x16x32 bf16.
// BK=64 (8 K-iterations, 2 MFMA k-steps each). LDS k-chunk slot = chunk^(row&7)
// swizzle -> 2-way-max bank aliasing (free). Last block folds the finalize.
__global__ __launch_bounds__(512) void simrow_kernel(
    const unsigned short* __restrict__ z, float* __restrict__ rowsum,
    const float* __restrict__ pos, unsigned int* __restrict__ counter,
    float* __restrict__ out) {
    __shared__ unsigned short As[128 * 64];  // 16 KB
    __shared__ unsigned short Bs[256 * 64];  // 32 KB
    __shared__ float rsum[128];
    __shared__ float csum[256];
    __shared__ float red[16];
    __shared__ unsigned int lastFlag;

    const int tid  = threadIdx.x;
    const int lane = tid & 63;
    const int wid  = tid >> 6;   // 0..7
    const int wr   = wid >> 2;   // 0..1  (row half)
    const int wc   = wid & 3;    // 0..3  (col quarter of 256)

    // block id -> (bi, p): start(bi) = NPAIR - ((65-bi)^2)/4
    const int t0 = blockIdx.x;
    int bi = 65 - (int)ceilf(sqrtf(4.0f * (float)(NPAIR - t0)));
    if (bi < 0) bi = 0;
    if (bi > NB - 1) bi = NB - 1;
    while (bi > 0 && (NPAIR - (((65 - bi) * (65 - bi)) >> 2)) > t0) --bi;
    while ((NPAIR - (((64 - bi) * (64 - bi)) >> 2)) <= t0) ++bi;
    const int p = t0 - (NPAIR - (((65 - bi) * (65 - bi)) >> 2));
    const int bj0 = bi + 2 * p;
    const bool valid1 = (bj0 + 1) < NB;
    const int row0 = bi * 128;
    const int c0 = bj0 * 128;
    const int c1 = valid1 ? c0 + 128 : c0;   // clamp: reuse tile0 data, gated out
    const bool diag0 = (bj0 == bi);

    if (tid < 128) rsum[tid] = 0.f;
    if (tid < 256) csum[tid] = 0.f;

    // staging decomposition: lane -> (row offset = lane>>3, slot = lane&7)
    const int srow   = lane >> 3;
    const int schunk = (lane & 7) ^ srow;    // global 16B chunk (XOR swizzle)

    f32x4 acc[4][4] = {};
    for (int kt = 0; kt < D_DIM / 64; ++kt) {
        const int k0 = kt * 64;
        #pragma unroll
        for (int i = 0; i < 2; ++i) {
            const int r = i * 64 + wid * 8 + srow;
            gl_lds16(z + (size_t)(row0 + r) * D_DIM + k0 + schunk * 8,
                     &As[(i * 64 + wid * 8) * 64]);
        }
        #pragma unroll
        for (int i = 0; i < 4; ++i) {
            const int r = i * 64 + wid * 8 + srow;   // 0..255
            const int grow = (r < 128) ? (c0 + r) : (c1 + r - 128);
            gl_lds16(z + (size_t)grow * D_DIM + k0 + schunk * 8,
                     &Bs[(i * 64 + wid * 8) * 64]);
        }
        __syncthreads();
        const int ml = lane & 15;
        const int kh = lane >> 4;
        #pragma unroll
        for (int s = 0; s < 2; ++s) {
            const int cq = s * 4 + kh;     // 16B chunk within 128B row
            bf16x8 af[4], bfr[4];
            #pragma unroll
            for (int mi = 0; mi < 4; ++mi) {
                const int r = wr * 64 + mi * 16 + ml;
                af[mi] = *(const bf16x8*)&As[r * 64 + ((cq ^ (r & 7)) * 8)];
            }
            #pragma unroll
            for (int ni = 0; ni < 4; ++ni) {
                const int r = wc * 64 + ni * 16 + ml;
                bfr[ni] = *(const bf16x8*)&Bs[r * 64 + ((cq ^ (r & 7)) * 8)];
            }
            #pragma unroll
            for (int mi = 0; mi < 4; ++mi)
                #pragma unroll
                for (int ni = 0; ni < 4; ++ni)
                    acc[mi][ni] = __builtin_amdgcn_mfma_f32_16x16x32_bf16(
                        af[mi], bfr[ni], acc[mi][ni], 0, 0, 0);
        }
        __syncthreads();
    }

    // epilogue: e = exp(2*sim), mask global diagonal; row sums + (symmetric) col sums
    const int quad = lane >> 4;
    const int cl   = lane & 15;
    const bool isT1 = (wc >= 2);
    const int cbase = (isT1 ? c1 : c0) + (wc & 1) * 64;
    const bool contrib = isT1 ? valid1 : true;
    float colacc[4] = {0.f, 0.f, 0.f, 0.f};
    #pragma unroll
    for (int mi = 0; mi < 4; ++mi) {
        #pragma unroll
        for (int r2 = 0; r2 < 4; ++r2) {
            const int lrow = wr * 64 + mi * 16 + quad * 4 + r2;
            const int irow = row0 + lrow;
            float s = 0.f;
            #pragma unroll
            for (int ni = 0; ni < 4; ++ni) {
                const int jcol = cbase + ni * 16 + cl;
                float e = __expf(TEMP_INV * acc[mi][ni][r2]);
                e = (irow == jcol || !contrib) ? 0.f : e;
                s += e;
                colacc[ni] += e;
            }
            s += __shfl_xor(s, 1);
            s += __shfl_xor(s, 2);
            s += __shfl_xor(s, 4);
            s += __shfl_xor(s, 8);
            if (cl == 0) atomicAdd(&rsum[lrow], s);
        }
    }
    const bool doCol = isT1 ? valid1 : (!diag0);
    if (doCol) {
        #pragma unroll
        for (int ni = 0; ni < 4; ++ni) {
            float c = colacc[ni];
            c += __shfl_xor(c, 16);
            c += __shfl_xor(c, 32);
            if (quad == 0) atomicAdd(&csum[wc * 64 + ni * 16 + cl], c);
        }
    }
    __syncthreads();
    if (tid < 128) {
        atomicAdd(&rowsum[row0 + tid], rsum[tid]);
        if (!diag0) atomicAdd(&rowsum[c0 + tid], csum[tid]);
    }
    if (tid >= 128 && tid < 256 && valid1)
        atomicAdd(&rowsum[c1 + tid - 128], csum[tid]);

    // ---- tail: last block computes the scalar loss ----
    if (tid == 0) {
        __threadfence();                         // release our rowsum adds
        unsigned int old = atomicAdd(counter, 1u);
        lastFlag = (old == NPAIR - 1) ? 1u : 0u;
    }
    __syncthreads();
    if (lastFlag) {
        __threadfence();                         // acquire others' adds
        float s = 0.f, pacc = 0.f;
        for (int i = tid; i < N_TOT; i += 512) {
            float rv = __hip_atomic_load(&rowsum[i], __ATOMIC_RELAXED,
                                         __HIP_MEMORY_SCOPE_AGENT);
            s += logf(rv);
        }
        for (int i = tid; i < B_ROWS; i += 512) pacc += pos[i];
        #pragma unroll
        for (int m = 32; m >= 1; m >>= 1) {
            s += __shfl_xor(s, m);
            pacc += __shfl_xor(pacc, m);
        }
        if (lane == 0) { red[wid] = s; red[8 + wid] = pacc; }
        __syncthreads();
        if (tid == 0) {
            float tot = 0.f, pt = 0.f;
            for (int i = 0; i < 8; ++i) { tot += red[i]; pt += red[8 + i]; }
            // loss = mean(log denom) - (2*posSum)/(temp*N)
            out[0] = tot / (float)N_TOT - pt * (2.0f * TEMP_INV / (float)N_TOT);
        }
    }
}

extern "C" void kernel_launch(void* const* d_in, const int* in_sizes, int n_in,
                              void* d_out, int out_size, void* d_ws, size_t ws_size,
                              hipStream_t stream) {
    const float* xi = (const float*)d_in[0];
    const float* xj = (const float*)d_in[1];
    float* out = (float*)d_out;
    char* ws = (char*)d_ws;

    unsigned short* z = (unsigned short*)ws;                       // 8 MB bf16
    float* rowsum = (float*)(ws + (size_t)N_TOT * D_DIM * 2);      // 32 KB
    float* pos = rowsum + N_TOT;                                   // 16 KB
    unsigned int* counter = (unsigned int*)(pos + B_ROWS);         // 4 B

    normpos_kernel<<<B_ROWS / 4, 256, 0, stream>>>(xi, xj, z, pos, rowsum, counter);
    simrow_kernel<<<NPAIR, 512, 0, stream>>>(z, rowsum, pos, counter, out);
}